// Round 2
// baseline (829.908 us; speedup 1.0000x reference)
//
#include <hip/hip_runtime.h>
#include <stdint.h>

typedef unsigned short u16;
typedef __attribute__((ext_vector_type(8))) short bf16x8;
typedef __attribute__((ext_vector_type(4))) float f32x4;

__device__ __forceinline__ float bf2f(u16 u) {
    unsigned v = ((unsigned)u) << 16;
    float f;
    __builtin_memcpy(&f, &v, 4);
    return f;
}
__device__ __forceinline__ u16 f2bf(float f) {
    unsigned x;
    __builtin_memcpy(&x, &f, 4);
    unsigned r = (x + 0x7fffu + ((x >> 16) & 1u)) >> 16;
    return (u16)r;
}

#define BM 128
#define BN 128
#define BK 32

#define GLDS(g, l) __builtin_amdgcn_global_load_lds( \
    (const __attribute__((address_space(1))) void*)(g), \
    (__attribute__((address_space(3))) void*)(l), 16, 0, 0)

// C = A @ B^T, A: [M x K] (lda), B: [N x K] (ldb), both bf16, fp32 acc.
// Optional f32 bias[col] + relu^2 epilogue. Output bf16 (outf32=0) or f32.
// blockIdx.z selects pointer set (two problems fused per launch);
// column offset in output = z * colstep.
__global__ __launch_bounds__(256) void gemm_bt(
    const u16* __restrict__ A0, const u16* __restrict__ A1, int lda,
    const u16* __restrict__ B0, const u16* __restrict__ B1, int ldb,
    const float* __restrict__ bias0, const float* __restrict__ bias1,
    void* __restrict__ out0, void* __restrict__ out1,
    int ldo, int colstep, int K, int relu2flag, int outf32)
{
    __shared__ __align__(16) u16 As[BM * BK];   // 8 KB
    __shared__ __align__(16) u16 Bs[BN * BK];   // 8 KB
    const int tid = threadIdx.x;
    const int z = blockIdx.z;
    const u16* A  = z ? A1 : A0;
    const u16* Bw = z ? B1 : B0;
    const int rowBase = blockIdx.y * BM;
    const int colBase = blockIdx.x * BN;
    const int wave = tid >> 6;
    const int lane = tid & 63;
    const int wm = (wave >> 1) * 64;
    const int wn = (wave & 1) * 64;
    const int mlane = lane & 15;
    const int quad  = lane >> 4;

    // 512 16B-chunks per 128x32 tile; 256 threads x 2 issues per matrix.
    const int ca = tid;
    const int cb = tid + 256;
    const int ra = ca >> 2, sa = ca & 3;
    const int rb = cb >> 2, sb = cb & 3;
    const u16* gAa = A  + (size_t)(rowBase + ra) * lda + sa * 8;
    const u16* gAb = A  + (size_t)(rowBase + rb) * lda + sb * 8;
    const u16* gBa = Bw + (size_t)(colBase + ra) * ldb + sa * 8;
    const u16* gBb = Bw + (size_t)(colBase + rb) * ldb + sb * 8;

    f32x4 acc[4][4] = {};

    for (int k0 = 0; k0 < K; k0 += BK) {
        GLDS(gAa + k0, As + ca * 8);
        GLDS(gAb + k0, As + cb * 8);
        GLDS(gBa + k0, Bs + ca * 8);
        GLDS(gBb + k0, Bs + cb * 8);
        __syncthreads();
        bf16x8 af[4], bfr[4];
        #pragma unroll
        for (int t = 0; t < 4; ++t) {
            af[t]  = *(const bf16x8*)(As + (wm + t * 16 + mlane) * BK + quad * 8);
            bfr[t] = *(const bf16x8*)(Bs + (wn + t * 16 + mlane) * BK + quad * 8);
        }
        #pragma unroll
        for (int i = 0; i < 4; ++i)
            #pragma unroll
            for (int j = 0; j < 4; ++j)
                acc[i][j] = __builtin_amdgcn_mfma_f32_16x16x32_bf16(af[i], bfr[j], acc[i][j], 0, 0, 0);
        __syncthreads();
    }

    const float* bias = z ? bias1 : bias0;
    const int coloff = z * colstep;
    float* outF = (float*)(z ? out1 : out0);
    u16*   outB = (u16*)  (z ? out1 : out0);
    #pragma unroll
    for (int j = 0; j < 4; ++j) {
        const int col = colBase + wn + j * 16 + mlane;
        const float bv = bias ? bias[col] : 0.0f;
        #pragma unroll
        for (int i = 0; i < 4; ++i) {
            const int rbse = rowBase + wm + i * 16 + quad * 4;
            #pragma unroll
            for (int r = 0; r < 4; ++r) {
                float v = acc[i][j][r] + bv;
                if (relu2flag) v = (v > 0.0f) ? v * v : 0.0f;
                const size_t ofs = (size_t)(rbse + r) * ldo + coloff + col;
                if (outf32) outF[ofs] = v;
                else        outB[ofs] = f2bf(v);
            }
        }
    }
}

// Convert x, u1_w, u2_w (f32) to bf16 into contiguous dst [xbf|u1bf|u2bf].
__global__ __launch_bounds__(256) void cvt_bf16(
    const float* __restrict__ x, const float* __restrict__ u1,
    const float* __restrict__ u2, u16* __restrict__ dst)
{
    const int idx4 = blockIdx.x * 256 + threadIdx.x;  // one float4 each
    const int NX = 8388608 / 4, NU = 3145728 / 4;     // 2097152, 786432
    const float4* src;
    int off;
    if (idx4 < NX)           { src = (const float4*)x;  off = idx4; }
    else if (idx4 < NX + NU) { src = (const float4*)u1; off = idx4 - NX; }
    else                     { src = (const float4*)u2; off = idx4 - NX - NU; }
    const float4 v = src[off];
    ushort4 o;
    o.x = f2bf(v.x); o.y = f2bf(v.y); o.z = f2bf(v.z); o.w = f2bf(v.w);
    ((ushort4*)dst)[idx4] = o;
}

// W1 = [v11 | v12 | b1^T], W2 = [v21 | v22 | b2^T], each [512 x 6656] bf16.
__global__ __launch_bounds__(256) void prep_wcat(
    const float* __restrict__ v11, const float* __restrict__ v12,
    const float* __restrict__ v21, const float* __restrict__ v22,
    const float* __restrict__ b1,  const float* __restrict__ b2,
    u16* __restrict__ W1, u16* __restrict__ W2)
{
    const int idx = blockIdx.x * 256 + threadIdx.x;   // 512*6656 exact
    const int n = idx / 6656;
    const int k = idx - n * 6656;
    float w1, w2;
    if (k < 3072)      { w1 = v11[n * 3072 + k];        w2 = v21[n * 3072 + k]; }
    else if (k < 6144) { w1 = v12[n * 3072 + k - 3072]; w2 = v22[n * 3072 + k - 3072]; }
    else               { w1 = b1[(k - 6144) * 512 + n]; w2 = b2[(k - 6144) * 512 + n]; }
    W1[idx] = f2bf(w1);
    W2[idx] = f2bf(w2);
}

// Per-token gating, in place on Y:
//  on entry: Y1[t, 0:3072] = x1[t] (from GEMM1), Y2[t, 3072:6144] = x2[t]
//  on exit:  Y1[t] = [gs1*x1 | sum_h t2*g1 | gs1], Y2[t] = [sum_h t1*g2 | gs2*x2 | gs2]
__global__ __launch_bounds__(256) void gating(
    const float* __restrict__ g1, const float* __restrict__ g2,
    u16* __restrict__ Y1, u16* __restrict__ Y2)
{
    __shared__ __align__(16) float g1s[3072], g2s[3072];   // 24 KB
    __shared__ __align__(16) u16 x1s[3072], x2s[3072];     // 12 KB
    __shared__ float tred[4][72];
    __shared__ float t1s[36], t2s[36];
    const int tid = threadIdx.x;
    const int wave = tid >> 6, lane = tid & 63;
    const size_t tok = blockIdx.x;
    const size_t gb = tok * 3072;
    const size_t yb = tok * 6656;

    #pragma unroll
    for (int j = 0; j < 3; ++j) {
        const int c = tid + j * 256;
        ((float4*)g1s)[c]  = ((const float4*)(g1 + gb))[c];
        ((float4*)g2s)[c]  = ((const float4*)(g2 + gb))[c];
        ((ushort4*)x1s)[c] = ((const ushort4*)(Y1 + yb))[c];
        ((ushort4*)x2s)[c] = ((const ushort4*)(Y2 + yb + 3072))[c];
    }
    __syncthreads();

    float t1p[36], t2p[36];
    #pragma unroll
    for (int p = 0; p < 36; ++p) { t1p[p] = 0.f; t2p[p] = 0.f; }
    float gsum1[2], gsum2[2];

    #pragma unroll
    for (int ii = 0; ii < 2; ++ii) {
        const int i = tid + ii * 256;   // expert index 0..511
        float g1v[6], g2v[6], x1v[6], x2v[6];
        #pragma unroll
        for (int h = 0; h < 6; ++h) { g1v[h] = g1s[h*512+i]; g2v[h] = g2s[h*512+i]; }
        #pragma unroll
        for (int m = 0; m < 6; ++m) { x1v[m] = bf2f(x1s[i*6+m]); x2v[m] = bf2f(x2s[i*6+m]); }
        float s1 = 0.f, s2 = 0.f;
        #pragma unroll
        for (int h = 0; h < 6; ++h) { s1 += g1v[h]; s2 += g2v[h]; }
        gsum1[ii] = s1; gsum2[ii] = s2;
        Y1[yb + 6144 + i] = f2bf(s1);
        Y2[yb + 6144 + i] = f2bf(s2);
        #pragma unroll
        for (int h = 0; h < 6; ++h)
            #pragma unroll
            for (int m = 0; m < 6; ++m) {
                t1p[h*6+m] += g1v[h] * x1v[m];
                t2p[h*6+m] += g2v[h] * x2v[m];
            }
    }
    // wave butterfly reduce 36+36 accumulators, then cross-wave in LDS
    #pragma unroll
    for (int p = 0; p < 36; ++p) {
        #pragma unroll
        for (int s = 1; s < 64; s <<= 1) {
            t1p[p] += __shfl_xor(t1p[p], s, 64);
            t2p[p] += __shfl_xor(t2p[p], s, 64);
        }
    }
    if (lane == 0) {
        #pragma unroll
        for (int p = 0; p < 36; ++p) { tred[wave][p] = t1p[p]; tred[wave][36+p] = t2p[p]; }
    }
    __syncthreads();
    if (tid < 72) {
        float s = tred[0][tid] + tred[1][tid] + tred[2][tid] + tred[3][tid];
        if (tid < 36) t1s[tid] = s; else t2s[tid - 36] = s;
    }
    __syncthreads();

    #pragma unroll
    for (int ii = 0; ii < 2; ++ii) {
        const int i = tid + ii * 256;
        float g1v[6], g2v[6];
        #pragma unroll
        for (int h = 0; h < 6; ++h) { g1v[h] = g1s[h*512+i]; g2v[h] = g2s[h*512+i]; }
        #pragma unroll
        for (int m = 0; m < 6; ++m) {
            const float a1 = gsum1[ii] * bf2f(x1s[i*6+m]);
            const float a2 = gsum2[ii] * bf2f(x2s[i*6+m]);
            float c1 = 0.f, c2 = 0.f;
            #pragma unroll
            for (int h = 0; h < 6; ++h) {
                c2 += t2s[h*6+m] * g1v[h];
                c1 += t1s[h*6+m] * g2v[h];
            }
            Y1[yb + i*6 + m]        = f2bf(a1);
            Y1[yb + 3072 + i*6 + m] = f2bf(c2);
            Y2[yb + i*6 + m]        = f2bf(c1);
            Y2[yb + 3072 + i*6 + m] = f2bf(a2);
        }
    }
}

extern "C" void kernel_launch(void* const* d_in, const int* in_sizes, int n_in,
                              void* d_out, int out_size, void* d_ws, size_t ws_size,
                              hipStream_t stream) {
    const float* x   = (const float*)d_in[0];
    const float* g1  = (const float*)d_in[1];
    const float* g2  = (const float*)d_in[2];
    const float* u1w = (const float*)d_in[3];
    const float* u1b = (const float*)d_in[4];
    const float* u2w = (const float*)d_in[5];
    const float* u2b = (const float*)d_in[6];
    const float* v11 = (const float*)d_in[7];
    const float* v12 = (const float*)d_in[8];
    const float* v21 = (const float*)d_in[9];
    const float* v22 = (const float*)d_in[10];
    const float* b1  = (const float*)d_in[11];
    const float* b2  = (const float*)d_in[12];
    float* out = (float*)d_out;

    // ws layout (bf16 elements), total ~261 MB
    u16* Y1   = (u16*)d_ws;                       // 8192*6656
    u16* Y2   = Y1 + (size_t)8192 * 6656;         // 8192*6656
    u16* xbf  = Y2 + (size_t)8192 * 6656;         // 8192*1024
    u16* u1bf = xbf + (size_t)8192 * 1024;        // 3072*1024
    u16* u2bf = u1bf + (size_t)3072 * 1024;       // 3072*1024
    u16* W1   = u2bf + (size_t)3072 * 1024;       // 512*6656
    u16* W2   = W1 + (size_t)512 * 6656;          // 512*6656

    // f32 -> bf16: [xbf|u1bf|u2bf] contiguous, 3670016 float4s = 14336*256
    cvt_bf16<<<dim3(14336), 256, 0, stream>>>(x, u1w, u2w, xbf);

    // weight concat (512*6656 = 13312 * 256)
    prep_wcat<<<dim3(13312), 256, 0, stream>>>(v11, v12, v21, v22, b1, b2, W1, W2);

    // up-proj GEMMs + bias + relu^2: write x1 -> Y1[:,0:3072], x2 -> Y2[:,3072:6144]
    gemm_bt<<<dim3(24, 64, 2), 256, 0, stream>>>(
        xbf, xbf, 1024, u1bf, u2bf, 1024, u1b, u2b, Y1, Y2, 6656, 3072, 1024, 1, 0);

    // per-token gating, in place on Y1/Y2
    gating<<<dim3(8192), 256, 0, stream>>>(g1, g2, Y1, Y2);

    // down-proj GEMMs: out[:, z*512 : z*512+512] = Y_z @ W_z^T  (f32 store)
    gemm_bt<<<dim3(4, 64, 2), 256, 0, stream>>>(
        Y1, Y2, 6656, W1, W2, 6656, nullptr, nullptr, out, out, 1024, 512, 6656, 0, 1);
}

// Round 3
// 764.852 us; speedup vs baseline: 1.0851x; 1.0851x over previous
//
#include <hip/hip_runtime.h>
#include <stdint.h>

typedef unsigned short u16;
typedef __attribute__((ext_vector_type(8))) short bf16x8;
typedef __attribute__((ext_vector_type(4))) float f32x4;

__device__ __forceinline__ float bf2f(u16 u) {
    unsigned v = ((unsigned)u) << 16;
    float f;
    __builtin_memcpy(&f, &v, 4);
    return f;
}
__device__ __forceinline__ u16 f2bf(float f) {
    unsigned x;
    __builtin_memcpy(&x, &f, 4);
    unsigned r = (x + 0x7fffu + ((x >> 16) & 1u)) >> 16;
    return (u16)r;
}

#define BM 128
#define BN 128
#define BK 32

#define GLDS(g, l) __builtin_amdgcn_global_load_lds( \
    (const __attribute__((address_space(1))) void*)(g), \
    (__attribute__((address_space(3))) void*)(l), 16, 0, 0)

// ---------------- GEMM1: C = A @ B^T, bias + relu^2, bf16 out ----------------
// A: [M x K] (lda), B: [N x K] (ldb). blockIdx.z selects problem (z).
__global__ __launch_bounds__(256) void gemm_bt(
    const u16* __restrict__ A0, const u16* __restrict__ A1, int lda,
    const u16* __restrict__ B0, const u16* __restrict__ B1, int ldb,
    const float* __restrict__ bias0, const float* __restrict__ bias1,
    u16* __restrict__ out0, u16* __restrict__ out1,
    int ldo, int colstep, int K)
{
    __shared__ __align__(16) u16 As[BM * BK];   // 8 KB
    __shared__ __align__(16) u16 Bs[BN * BK];   // 8 KB
    const int tid = threadIdx.x;
    const int z = blockIdx.z;
    const u16* A  = z ? A1 : A0;
    const u16* Bw = z ? B1 : B0;
    const int rowBase = blockIdx.y * BM;
    const int colBase = blockIdx.x * BN;
    const int wave = tid >> 6;
    const int lane = tid & 63;
    const int wm = (wave >> 1) * 64;
    const int wn = (wave & 1) * 64;
    const int mlane = lane & 15;
    const int quad  = lane >> 4;

    const int ca = tid;
    const int cb = tid + 256;
    const int ra = ca >> 2, sa = ca & 3;
    const int rb = cb >> 2, sb = cb & 3;
    const u16* gAa = A  + (size_t)(rowBase + ra) * lda + sa * 8;
    const u16* gAb = A  + (size_t)(rowBase + rb) * lda + sb * 8;
    const u16* gBa = Bw + (size_t)(colBase + ra) * ldb + sa * 8;
    const u16* gBb = Bw + (size_t)(colBase + rb) * ldb + sb * 8;

    f32x4 acc[4][4] = {};

    for (int k0 = 0; k0 < K; k0 += BK) {
        GLDS(gAa + k0, As + ca * 8);
        GLDS(gAb + k0, As + cb * 8);
        GLDS(gBa + k0, Bs + ca * 8);
        GLDS(gBb + k0, Bs + cb * 8);
        __syncthreads();
        bf16x8 af[4], bfr[4];
        #pragma unroll
        for (int t = 0; t < 4; ++t) {
            af[t]  = *(const bf16x8*)(As + (wm + t * 16 + mlane) * BK + quad * 8);
            bfr[t] = *(const bf16x8*)(Bs + (wn + t * 16 + mlane) * BK + quad * 8);
        }
        #pragma unroll
        for (int i = 0; i < 4; ++i)
            #pragma unroll
            for (int j = 0; j < 4; ++j)
                acc[i][j] = __builtin_amdgcn_mfma_f32_16x16x32_bf16(af[i], bfr[j], acc[i][j], 0, 0, 0);
        __syncthreads();
    }

    const float* bias = z ? bias1 : bias0;
    const int coloff = z * colstep;
    u16* outp = z ? out1 : out0;
    #pragma unroll
    for (int j = 0; j < 4; ++j) {
        const int col = colBase + wn + j * 16 + mlane;
        const float bv = bias[col];
        #pragma unroll
        for (int i = 0; i < 4; ++i) {
            const int rbse = rowBase + wm + i * 16 + quad * 4;
            #pragma unroll
            for (int r = 0; r < 4; ++r) {
                float v = acc[i][j][r] + bv;
                v = (v > 0.0f) ? v * v : 0.0f;
                outp[(size_t)(rbse + r) * ldo + coloff + col] = f2bf(v);
            }
        }
    }
}

// ---------------- GEMM2: split-K, f32 out/partials ----------------
// 1D grid, L = blockIdx.x over 4 * 64 * (2*nsplit) blocks.
// z2 = L % (2*nsplit) keeps each (z,split) on one XCD (blockIdx%8 heuristic).
__global__ __launch_bounds__(256) void gemm2_split(
    const u16* __restrict__ Y1, const u16* __restrict__ Y2,
    const u16* __restrict__ W1, const u16* __restrict__ W2,
    float* __restrict__ out, float* __restrict__ pbase, int nsplit)
{
    __shared__ __align__(16) u16 As[BM * BK];
    __shared__ __align__(16) u16 Bs[BN * BK];
    const int tid = threadIdx.x;
    const int z2cnt = 2 * nsplit;
    const int L = blockIdx.x;
    const int z2 = L % z2cnt;
    const int q  = L / z2cnt;
    const int bx = q & 3;
    const int by = q >> 2;
    const int z = z2 & 1;
    const int split = z2 >> 1;
    const int Ks = 6656 / nsplit;
    const int kbeg = split * Ks;

    const u16* A  = z ? Y2 : Y1;
    const u16* Bw = z ? W2 : W1;
    const int rowBase = by * BM;
    const int colBase = bx * BN;
    const int wave = tid >> 6;
    const int lane = tid & 63;
    const int wm = (wave >> 1) * 64;
    const int wn = (wave & 1) * 64;
    const int mlane = lane & 15;
    const int quad  = lane >> 4;

    const int ca = tid;
    const int cb = tid + 256;
    const int ra = ca >> 2, sa = ca & 3;
    const int rb = cb >> 2, sb = cb & 3;
    const u16* gAa = A  + (size_t)(rowBase + ra) * 6656 + sa * 8 + kbeg;
    const u16* gAb = A  + (size_t)(rowBase + rb) * 6656 + sb * 8 + kbeg;
    const u16* gBa = Bw + (size_t)(colBase + ra) * 6656 + sa * 8 + kbeg;
    const u16* gBb = Bw + (size_t)(colBase + rb) * 6656 + sb * 8 + kbeg;

    f32x4 acc[4][4] = {};

    for (int k0 = 0; k0 < Ks; k0 += BK) {
        GLDS(gAa + k0, As + ca * 8);
        GLDS(gAb + k0, As + cb * 8);
        GLDS(gBa + k0, Bs + ca * 8);
        GLDS(gBb + k0, Bs + cb * 8);
        __syncthreads();
        bf16x8 af[4], bfr[4];
        #pragma unroll
        for (int t = 0; t < 4; ++t) {
            af[t]  = *(const bf16x8*)(As + (wm + t * 16 + mlane) * BK + quad * 8);
            bfr[t] = *(const bf16x8*)(Bs + (wn + t * 16 + mlane) * BK + quad * 8);
        }
        #pragma unroll
        for (int i = 0; i < 4; ++i)
            #pragma unroll
            for (int j = 0; j < 4; ++j)
                acc[i][j] = __builtin_amdgcn_mfma_f32_16x16x32_bf16(af[i], bfr[j], acc[i][j], 0, 0, 0);
        __syncthreads();
    }

    float* dst = (split == 0) ? out : (pbase + (size_t)(split - 1) * 8192 * 1024);
    const int coloff = z * 512;
    #pragma unroll
    for (int j = 0; j < 4; ++j) {
        const int col = colBase + wn + j * 16 + mlane;
        #pragma unroll
        for (int i = 0; i < 4; ++i) {
            const int rbse = rowBase + wm + i * 16 + quad * 4;
            #pragma unroll
            for (int r = 0; r < 4; ++r)
                dst[(size_t)(rbse + r) * 1024 + coloff + col] = acc[i][j][r];
        }
    }
}

// out += sum of nadd partial buffers (each 8192*1024 f32), float4-vectorized.
__global__ __launch_bounds__(256) void reduce_add(
    float4* __restrict__ out, const float4* __restrict__ p, int nadd)
{
    const int i = blockIdx.x * 256 + threadIdx.x;   // 2,097,152 float4s
    float4 v = out[i];
    for (int k = 0; k < nadd; ++k) {
        const float4 a = p[(size_t)k * 2097152 + i];
        v.x += a.x; v.y += a.y; v.z += a.z; v.w += a.w;
    }
    out[i] = v;
}

// Convert x, u1_w, u2_w (f32) to bf16 into contiguous dst [xbf|u1bf|u2bf].
__global__ __launch_bounds__(256) void cvt_bf16(
    const float* __restrict__ x, const float* __restrict__ u1,
    const float* __restrict__ u2, u16* __restrict__ dst)
{
    const int idx4 = blockIdx.x * 256 + threadIdx.x;  // one float4 each
    const int NX = 8388608 / 4, NU = 3145728 / 4;
    const float4* src;
    int off;
    if (idx4 < NX)           { src = (const float4*)x;  off = idx4; }
    else if (idx4 < NX + NU) { src = (const float4*)u1; off = idx4 - NX; }
    else                     { src = (const float4*)u2; off = idx4 - NX - NU; }
    const float4 v = src[off];
    ushort4 o;
    o.x = f2bf(v.x); o.y = f2bf(v.y); o.z = f2bf(v.z); o.w = f2bf(v.w);
    ((ushort4*)dst)[idx4] = o;
}

// W1 = [v11 | v12 | b1^T], W2 = [v21 | v22 | b2^T], each [512 x 6656] bf16.
__global__ __launch_bounds__(256) void prep_wcat(
    const float* __restrict__ v11, const float* __restrict__ v12,
    const float* __restrict__ v21, const float* __restrict__ v22,
    const float* __restrict__ b1,  const float* __restrict__ b2,
    u16* __restrict__ W1, u16* __restrict__ W2)
{
    const int idx = blockIdx.x * 256 + threadIdx.x;   // 512*6656 exact
    const int n = idx / 6656;
    const int k = idx - n * 6656;
    float w1, w2;
    if (k < 3072)      { w1 = v11[n * 3072 + k];        w2 = v21[n * 3072 + k]; }
    else if (k < 6144) { w1 = v12[n * 3072 + k - 3072]; w2 = v22[n * 3072 + k - 3072]; }
    else               { w1 = b1[(k - 6144) * 512 + n]; w2 = b2[(k - 6144) * 512 + n]; }
    W1[idx] = f2bf(w1);
    W2[idx] = f2bf(w2);
}

// Per-token gating, in place on Y:
//  entry: Y1[t, 0:3072] = x1[t], Y2[t, 3072:6144] = x2[t]
//  exit:  Y1[t] = [gs1*x1 | sum_h t2*g1 | gs1], Y2[t] = [sum_h t1*g2 | gs2*x2 | gs2]
__global__ __launch_bounds__(256) void gating(
    const float* __restrict__ g1, const float* __restrict__ g2,
    u16* __restrict__ Y1, u16* __restrict__ Y2)
{
    __shared__ __align__(16) float g1s[3072], g2s[3072];   // 24 KB
    __shared__ __align__(16) u16 x1s[3072], x2s[3072];     // 12 KB
    __shared__ float tred[4][72];
    __shared__ float t1s[36], t2s[36];
    const int tid = threadIdx.x;
    const int wave = tid >> 6, lane = tid & 63;
    const size_t tok = blockIdx.x;
    const size_t gb = tok * 3072;
    const size_t yb = tok * 6656;

    #pragma unroll
    for (int j = 0; j < 3; ++j) {
        const int c = tid + j * 256;
        ((float4*)g1s)[c]  = ((const float4*)(g1 + gb))[c];
        ((float4*)g2s)[c]  = ((const float4*)(g2 + gb))[c];
        ((ushort4*)x1s)[c] = ((const ushort4*)(Y1 + yb))[c];
        ((ushort4*)x2s)[c] = ((const ushort4*)(Y2 + yb + 3072))[c];
    }
    __syncthreads();

    float t1p[36], t2p[36];
    #pragma unroll
    for (int p = 0; p < 36; ++p) { t1p[p] = 0.f; t2p[p] = 0.f; }
    float gsum1[2], gsum2[2];

    #pragma unroll
    for (int ii = 0; ii < 2; ++ii) {
        const int i = tid + ii * 256;
        float g1v[6], g2v[6], x1v[6], x2v[6];
        #pragma unroll
        for (int h = 0; h < 6; ++h) { g1v[h] = g1s[h*512+i]; g2v[h] = g2s[h*512+i]; }
        #pragma unroll
        for (int m = 0; m < 6; ++m) { x1v[m] = bf2f(x1s[i*6+m]); x2v[m] = bf2f(x2s[i*6+m]); }
        float s1 = 0.f, s2 = 0.f;
        #pragma unroll
        for (int h = 0; h < 6; ++h) { s1 += g1v[h]; s2 += g2v[h]; }
        gsum1[ii] = s1; gsum2[ii] = s2;
        Y1[yb + 6144 + i] = f2bf(s1);
        Y2[yb + 6144 + i] = f2bf(s2);
        #pragma unroll
        for (int h = 0; h < 6; ++h)
            #pragma unroll
            for (int m = 0; m < 6; ++m) {
                t1p[h*6+m] += g1v[h] * x1v[m];
                t2p[h*6+m] += g2v[h] * x2v[m];
            }
    }
    #pragma unroll
    for (int p = 0; p < 36; ++p) {
        #pragma unroll
        for (int s = 1; s < 64; s <<= 1) {
            t1p[p] += __shfl_xor(t1p[p], s, 64);
            t2p[p] += __shfl_xor(t2p[p], s, 64);
        }
    }
    if (lane == 0) {
        #pragma unroll
        for (int p = 0; p < 36; ++p) { tred[wave][p] = t1p[p]; tred[wave][36+p] = t2p[p]; }
    }
    __syncthreads();
    if (tid < 72) {
        float s = tred[0][tid] + tred[1][tid] + tred[2][tid] + tred[3][tid];
        if (tid < 36) t1s[tid] = s; else t2s[tid - 36] = s;
    }
    __syncthreads();

    #pragma unroll
    for (int ii = 0; ii < 2; ++ii) {
        const int i = tid + ii * 256;
        float g1v[6], g2v[6];
        #pragma unroll
        for (int h = 0; h < 6; ++h) { g1v[h] = g1s[h*512+i]; g2v[h] = g2s[h*512+i]; }
        #pragma unroll
        for (int m = 0; m < 6; ++m) {
            const float a1 = gsum1[ii] * bf2f(x1s[i*6+m]);
            const float a2 = gsum2[ii] * bf2f(x2s[i*6+m]);
            float c1 = 0.f, c2 = 0.f;
            #pragma unroll
            for (int h = 0; h < 6; ++h) {
                c2 += t2s[h*6+m] * g1v[h];
                c1 += t1s[h*6+m] * g2v[h];
            }
            Y1[yb + i*6 + m]        = f2bf(a1);
            Y1[yb + 3072 + i*6 + m] = f2bf(c2);
            Y2[yb + i*6 + m]        = f2bf(c1);
            Y2[yb + 3072 + i*6 + m] = f2bf(a2);
        }
    }
}

extern "C" void kernel_launch(void* const* d_in, const int* in_sizes, int n_in,
                              void* d_out, int out_size, void* d_ws, size_t ws_size,
                              hipStream_t stream) {
    const float* x   = (const float*)d_in[0];
    const float* g1  = (const float*)d_in[1];
    const float* g2  = (const float*)d_in[2];
    const float* u1w = (const float*)d_in[3];
    const float* u1b = (const float*)d_in[4];
    const float* u2w = (const float*)d_in[5];
    const float* u2b = (const float*)d_in[6];
    const float* v11 = (const float*)d_in[7];
    const float* v12 = (const float*)d_in[8];
    const float* v21 = (const float*)d_in[9];
    const float* v22 = (const float*)d_in[10];
    const float* b1  = (const float*)d_in[11];
    const float* b2  = (const float*)d_in[12];
    float* out = (float*)d_out;

    // ws layout (bytes): Y1,Y2 | xbf,u1bf,u2bf | W1,W2 | split-K partials
    u16* Y1   = (u16*)d_ws;                       // 8192*6656
    u16* Y2   = Y1 + (size_t)8192 * 6656;
    u16* xbf  = Y2 + (size_t)8192 * 6656;         // 8192*1024
    u16* u1bf = xbf + (size_t)8192 * 1024;        // 3072*1024
    u16* u2bf = u1bf + (size_t)3072 * 1024;
    u16* W1   = u2bf + (size_t)3072 * 1024;       // 512*6656
    u16* W2   = W1 + (size_t)512 * 6656;
    float* part = (float*)(W2 + (size_t)512 * 6656);

    const size_t base = (size_t)(W2 + (size_t)512 * 6656 - (u16*)d_ws) * 2;
    const size_t pbytes = (size_t)8192 * 1024 * 4;
    int nsplit = 1;
    if (ws_size >= base + 3 * pbytes) nsplit = 4;
    else if (ws_size >= base + pbytes) nsplit = 2;

    cvt_bf16<<<dim3(14336), 256, 0, stream>>>(x, u1w, u2w, xbf);
    prep_wcat<<<dim3(13312), 256, 0, stream>>>(v11, v12, v21, v22, b1, b2, W1, W2);

    // up-proj + bias + relu^2: x1 -> Y1[:,0:3072], x2 -> Y2[:,3072:6144]
    gemm_bt<<<dim3(24, 64, 2), 256, 0, stream>>>(
        xbf, xbf, 1024, u1bf, u2bf, 1024, u1b, u2b, Y1, Y2, 6656, 3072, 1024);

    gating<<<dim3(8192), 256, 0, stream>>>(g1, g2, Y1, Y2);

    // down-proj, split-K: out[:, z*512:+512] = Y_z @ W_z^T
    gemm2_split<<<dim3(4 * 64 * 2 * nsplit), 256, 0, stream>>>(
        Y1, Y2, W1, W2, out, part, nsplit);
    if (nsplit > 1)
        reduce_add<<<dim3(8192), 256, 0, stream>>>(
            (float4*)out, (const float4*)part, nsplit - 1);
}

// Round 4
// 668.542 us; speedup vs baseline: 1.2414x; 1.1441x over previous
//
#include <hip/hip_runtime.h>
#include <stdint.h>

typedef unsigned short u16;
typedef unsigned int u32;
typedef __attribute__((ext_vector_type(8))) short bf16x8;
typedef __attribute__((ext_vector_type(4))) float f32x4;

__device__ __forceinline__ float bf2f(u16 u) {
    unsigned v = ((unsigned)u) << 16;
    float f;
    __builtin_memcpy(&f, &v, 4);
    return f;
}
__device__ __forceinline__ u16 f2bf(float f) {
    unsigned x;
    __builtin_memcpy(&x, &f, 4);
    unsigned r = (x + 0x7fffu + ((x >> 16) & 1u)) >> 16;
    return (u16)r;
}

#define BM 128
#define BN 128
#define BK 32

#define GLDS(g, l) __builtin_amdgcn_global_load_lds( \
    (const __attribute__((address_space(1))) void*)(g), \
    (__attribute__((address_space(3))) void*)(l), 16, 0, 0)

// ---------------- GEMM1: C = A @ B^T, bias + relu^2, bf16 out ----------------
__global__ __launch_bounds__(256) void gemm_bt(
    const u16* __restrict__ A0, const u16* __restrict__ A1, int lda,
    const u16* __restrict__ B0, const u16* __restrict__ B1, int ldb,
    const float* __restrict__ bias0, const float* __restrict__ bias1,
    u16* __restrict__ out0, u16* __restrict__ out1,
    int ldo, int colstep, int K)
{
    __shared__ __align__(16) u16 As[BM * BK];   // 8 KB
    __shared__ __align__(16) u16 Bs[BN * BK];   // 8 KB
    const int tid = threadIdx.x;
    const int z = blockIdx.z;
    const u16* A  = z ? A1 : A0;
    const u16* Bw = z ? B1 : B0;
    const int rowBase = blockIdx.y * BM;
    const int colBase = blockIdx.x * BN;
    const int wave = tid >> 6;
    const int lane = tid & 63;
    const int wm = (wave >> 1) * 64;
    const int wn = (wave & 1) * 64;
    const int mlane = lane & 15;
    const int quad  = lane >> 4;

    const int ca = tid;
    const int cb = tid + 256;
    const int ra = ca >> 2, sa = ca & 3;
    const int rb = cb >> 2, sb = cb & 3;
    const u16* gAa = A  + (size_t)(rowBase + ra) * lda + sa * 8;
    const u16* gAb = A  + (size_t)(rowBase + rb) * lda + sb * 8;
    const u16* gBa = Bw + (size_t)(colBase + ra) * ldb + sa * 8;
    const u16* gBb = Bw + (size_t)(colBase + rb) * ldb + sb * 8;

    f32x4 acc[4][4] = {};

    for (int k0 = 0; k0 < K; k0 += BK) {
        GLDS(gAa + k0, As + ca * 8);
        GLDS(gAb + k0, As + cb * 8);
        GLDS(gBa + k0, Bs + ca * 8);
        GLDS(gBb + k0, Bs + cb * 8);
        __syncthreads();
        bf16x8 af[4], bfr[4];
        #pragma unroll
        for (int t = 0; t < 4; ++t) {
            af[t]  = *(const bf16x8*)(As + (wm + t * 16 + mlane) * BK + quad * 8);
            bfr[t] = *(const bf16x8*)(Bs + (wn + t * 16 + mlane) * BK + quad * 8);
        }
        #pragma unroll
        for (int i = 0; i < 4; ++i)
            #pragma unroll
            for (int j = 0; j < 4; ++j)
                acc[i][j] = __builtin_amdgcn_mfma_f32_16x16x32_bf16(af[i], bfr[j], acc[i][j], 0, 0, 0);
        __syncthreads();
    }

    const float* bias = z ? bias1 : bias0;
    const int coloff = z * colstep;
    u16* outp = z ? out1 : out0;
    #pragma unroll
    for (int j = 0; j < 4; ++j) {
        const int col = colBase + wn + j * 16 + mlane;
        const float bv = bias[col];
        #pragma unroll
        for (int i = 0; i < 4; ++i) {
            const int rbse = rowBase + wm + i * 16 + quad * 4;
            #pragma unroll
            for (int r = 0; r < 4; ++r) {
                float v = acc[i][j][r] + bv;
                v = (v > 0.0f) ? v * v : 0.0f;
                outp[(size_t)(rbse + r) * ldo + coloff + col] = f2bf(v);
            }
        }
    }
}

// ---------------- GEMM2: split-K, f32 out/partials ----------------
__global__ __launch_bounds__(256) void gemm2_split(
    const u16* __restrict__ Y1, const u16* __restrict__ Y2,
    const u16* __restrict__ W1, const u16* __restrict__ W2,
    float* __restrict__ out, float* __restrict__ pbase, int nsplit)
{
    __shared__ __align__(16) u16 As[BM * BK];
    __shared__ __align__(16) u16 Bs[BN * BK];
    const int tid = threadIdx.x;
    const int z2cnt = 2 * nsplit;
    const int L = blockIdx.x;
    const int z2 = L % z2cnt;
    const int q  = L / z2cnt;
    const int bx = q & 3;
    const int by = q >> 2;
    const int z = z2 & 1;
    const int split = z2 >> 1;
    const int Ks = 6656 / nsplit;
    const int kbeg = split * Ks;

    const u16* A  = z ? Y2 : Y1;
    const u16* Bw = z ? W2 : W1;
    const int rowBase = by * BM;
    const int colBase = bx * BN;
    const int wave = tid >> 6;
    const int lane = tid & 63;
    const int wm = (wave >> 1) * 64;
    const int wn = (wave & 1) * 64;
    const int mlane = lane & 15;
    const int quad  = lane >> 4;

    const int ca = tid;
    const int cb = tid + 256;
    const int ra = ca >> 2, sa = ca & 3;
    const int rb = cb >> 2, sb = cb & 3;
    const u16* gAa = A  + (size_t)(rowBase + ra) * 6656 + sa * 8 + kbeg;
    const u16* gAb = A  + (size_t)(rowBase + rb) * 6656 + sb * 8 + kbeg;
    const u16* gBa = Bw + (size_t)(colBase + ra) * 6656 + sa * 8 + kbeg;
    const u16* gBb = Bw + (size_t)(colBase + rb) * 6656 + sb * 8 + kbeg;

    f32x4 acc[4][4] = {};

    for (int k0 = 0; k0 < Ks; k0 += BK) {
        GLDS(gAa + k0, As + ca * 8);
        GLDS(gAb + k0, As + cb * 8);
        GLDS(gBa + k0, Bs + ca * 8);
        GLDS(gBb + k0, Bs + cb * 8);
        __syncthreads();
        bf16x8 af[4], bfr[4];
        #pragma unroll
        for (int t = 0; t < 4; ++t) {
            af[t]  = *(const bf16x8*)(As + (wm + t * 16 + mlane) * BK + quad * 8);
            bfr[t] = *(const bf16x8*)(Bs + (wn + t * 16 + mlane) * BK + quad * 8);
        }
        #pragma unroll
        for (int i = 0; i < 4; ++i)
            #pragma unroll
            for (int j = 0; j < 4; ++j)
                acc[i][j] = __builtin_amdgcn_mfma_f32_16x16x32_bf16(af[i], bfr[j], acc[i][j], 0, 0, 0);
        __syncthreads();
    }

    float* dst = (split == 0) ? out : (pbase + (size_t)(split - 1) * 8192 * 1024);
    const int coloff = z * 512;
    #pragma unroll
    for (int j = 0; j < 4; ++j) {
        const int col = colBase + wn + j * 16 + mlane;
        #pragma unroll
        for (int i = 0; i < 4; ++i) {
            const int rbse = rowBase + wm + i * 16 + quad * 4;
            #pragma unroll
            for (int r = 0; r < 4; ++r)
                dst[(size_t)(rbse + r) * 1024 + coloff + col] = acc[i][j][r];
        }
    }
}

__global__ __launch_bounds__(256) void reduce_add(
    float4* __restrict__ out, const float4* __restrict__ p, int nadd)
{
    const int i = blockIdx.x * 256 + threadIdx.x;
    float4 v = out[i];
    for (int k = 0; k < nadd; ++k) {
        const float4 a = p[(size_t)k * 2097152 + i];
        v.x += a.x; v.y += a.y; v.z += a.z; v.w += a.w;
    }
    out[i] = v;
}

__global__ __launch_bounds__(256) void cvt_bf16(
    const float* __restrict__ x, const float* __restrict__ u1,
    const float* __restrict__ u2, u16* __restrict__ dst)
{
    const int idx4 = blockIdx.x * 256 + threadIdx.x;
    const int NX = 8388608 / 4, NU = 3145728 / 4;
    const float4* src;
    int off;
    if (idx4 < NX)           { src = (const float4*)x;  off = idx4; }
    else if (idx4 < NX + NU) { src = (const float4*)u1; off = idx4 - NX; }
    else                     { src = (const float4*)u2; off = idx4 - NX - NU; }
    const float4 v = src[off];
    ushort4 o;
    o.x = f2bf(v.x); o.y = f2bf(v.y); o.z = f2bf(v.z); o.w = f2bf(v.w);
    ((ushort4*)dst)[idx4] = o;
}

__global__ __launch_bounds__(256) void prep_wcat(
    const float* __restrict__ v11, const float* __restrict__ v12,
    const float* __restrict__ v21, const float* __restrict__ v22,
    const float* __restrict__ b1,  const float* __restrict__ b2,
    u16* __restrict__ W1, u16* __restrict__ W2)
{
    const int idx = blockIdx.x * 256 + threadIdx.x;
    const int n = idx / 6656;
    const int k = idx - n * 6656;
    float w1, w2;
    if (k < 3072)      { w1 = v11[n * 3072 + k];        w2 = v21[n * 3072 + k]; }
    else if (k < 6144) { w1 = v12[n * 3072 + k - 3072]; w2 = v22[n * 3072 + k - 3072]; }
    else               { w1 = b1[(k - 6144) * 512 + n]; w2 = b2[(k - 6144) * 512 + n]; }
    W1[idx] = f2bf(w1);
    W2[idx] = f2bf(w2);
}

// ---------------- gating: MFMA t-matrices, no shuffle reduction ----------------
// entry: Y1[t, 0:3072] = x1[t], Y2[t, 3072:6144] = x2[t]
// exit:  Y1[t] = [gs1*x1 | sum_h t2*g1 | gs1], Y2[t] = [sum_h t1*g2 | gs2*x2 | gs2]
// LDS: sm = [g1b(3072) | xT1(3072) | g2b(3072) | xT2(3072) | pad to 17408]
// (pad covers MFMA fragment over-reads of rows 6..15; garbage rows only feed
//  unused D cells since D[i][j] mixes only A-row i with B-row j.)
__global__ __launch_bounds__(256) void gating(
    const float* __restrict__ g1, const float* __restrict__ g2,
    u16* __restrict__ Y1, u16* __restrict__ Y2)
{
    __shared__ __align__(16) u16 sm[17408];          // 34.8 KB
    __shared__ float tls[72];                        // t1s[36] | t2s[36]
    u16* g1b = sm;
    u16* xT1 = sm + 3072;
    u16* g2b = sm + 6144;
    u16* xT2 = sm + 9216;
    const int tid = threadIdx.x;
    const int wave = tid >> 6, lane = tid & 63;
    const size_t tok = blockIdx.x;
    const size_t gb = tok * 3072;
    const size_t yb = tok * 6656;

    // stage g (f32 -> bf16, coalesced) and x (transposed scatter)
    #pragma unroll
    for (int j = 0; j < 3; ++j) {
        const int c = tid + j * 256;
        float4 a = ((const float4*)(g1 + gb))[c];
        float4 b = ((const float4*)(g2 + gb))[c];
        ushort4 oa, ob;
        oa.x = f2bf(a.x); oa.y = f2bf(a.y); oa.z = f2bf(a.z); oa.w = f2bf(a.w);
        ob.x = f2bf(b.x); ob.y = f2bf(b.y); ob.z = f2bf(b.z); ob.w = f2bf(b.w);
        ((ushort4*)g1b)[c] = oa;
        ((ushort4*)g2b)[c] = ob;
        ushort4 xv1 = ((const ushort4*)(Y1 + yb))[c];
        ushort4 xv2 = ((const ushort4*)(Y2 + yb + 3072))[c];
        const u16 v1[4] = {xv1.x, xv1.y, xv1.z, xv1.w};
        const u16 v2[4] = {xv2.x, xv2.y, xv2.z, xv2.w};
        #pragma unroll
        for (int q = 0; q < 4; ++q) {
            const int e = c * 4 + q;
            const int i = e / 6;
            const int m = e - 6 * i;
            xT1[m * 512 + i] = v1[q];
            xT2[m * 512 + i] = v2[q];
        }
    }
    __syncthreads();

    // t1 (wave 0) / t2 (wave 1): 6x512 @ 512x6 via 16 MFMAs each
    if (wave < 2) {
        const u16* Ab = wave ? g2b : g1b;
        const u16* Bb = wave ? xT2 : xT1;
        const int fofs = (lane & 15) * 512 + (lane >> 4) * 8;
        f32x4 acc = {};
        #pragma unroll
        for (int k0 = 0; k0 < 512; k0 += 32) {
            bf16x8 af = *(const bf16x8*)(Ab + fofs + k0);
            bf16x8 bf = *(const bf16x8*)(Bb + fofs + k0);
            acc = __builtin_amdgcn_mfma_f32_16x16x32_bf16(af, bf, acc, 0, 0, 0);
        }
        const int col = lane & 15;
        const int rowb = (lane >> 4) * 4;
        float* ts = tls + wave * 36;
        #pragma unroll
        for (int r = 0; r < 4; ++r) {
            const int row = rowb + r;
            if (row < 6 && col < 6) ts[row * 6 + col] = acc[r];
        }
    }
    __syncthreads();

    // phase 2: experts 2t, 2t+1; packed dword stores
    const int t = tid;
    u32* Y1d = (u32*)(Y1 + yb);
    u32* Y2d = (u32*)(Y2 + yb);
    float sp1[2], sp2[2];
    #pragma unroll
    for (int e = 0; e < 2; ++e) {
        const int i = 2 * t + e;
        float g1v[6], g2v[6];
        float s1 = 0.f, s2 = 0.f;
        #pragma unroll
        for (int h = 0; h < 6; ++h) {
            g1v[h] = bf2f(g1b[h * 512 + i]); s1 += g1v[h];
            g2v[h] = bf2f(g2b[h * 512 + i]); s2 += g2v[h];
        }
        sp1[e] = s1; sp2[e] = s2;
        u32 pa1[3], pc2[3], pc1[3], pa2[3];
        #pragma unroll
        for (int mq = 0; mq < 3; ++mq) {
            u32 wa1 = 0, wc2 = 0, wc1 = 0, wa2 = 0;
            #pragma unroll
            for (int half = 0; half < 2; ++half) {
                const int m = mq * 2 + half;
                const float x1 = bf2f(xT1[m * 512 + i]);
                const float x2 = bf2f(xT2[m * 512 + i]);
                const float a1 = s1 * x1;
                const float a2 = s2 * x2;
                float c1 = 0.f, c2 = 0.f;
                #pragma unroll
                for (int h = 0; h < 6; ++h) {
                    c2 += tls[36 + h * 6 + m] * g1v[h];
                    c1 += tls[h * 6 + m] * g2v[h];
                }
                const int sh = half * 16;
                wa1 |= ((u32)f2bf(a1)) << sh;
                wc2 |= ((u32)f2bf(c2)) << sh;
                wc1 |= ((u32)f2bf(c1)) << sh;
                wa2 |= ((u32)f2bf(a2)) << sh;
            }
            pa1[mq] = wa1; pc2[mq] = wc2; pc1[mq] = wc1; pa2[mq] = wa2;
        }
        const int base = 6 * t + 3 * e;
        #pragma unroll
        for (int mq = 0; mq < 3; ++mq) {
            Y1d[base + mq]        = pa1[mq];
            Y1d[1536 + base + mq] = pc2[mq];
            Y2d[base + mq]        = pc1[mq];
            Y2d[1536 + base + mq] = pa2[mq];
        }
    }
    Y1d[3072 + t] = (u32)f2bf(sp1[0]) | (((u32)f2bf(sp1[1])) << 16);
    Y2d[3072 + t] = (u32)f2bf(sp2[0]) | (((u32)f2bf(sp2[1])) << 16);
}

extern "C" void kernel_launch(void* const* d_in, const int* in_sizes, int n_in,
                              void* d_out, int out_size, void* d_ws, size_t ws_size,
                              hipStream_t stream) {
    const float* x   = (const float*)d_in[0];
    const float* g1  = (const float*)d_in[1];
    const float* g2  = (const float*)d_in[2];
    const float* u1w = (const float*)d_in[3];
    const float* u1b = (const float*)d_in[4];
    const float* u2w = (const float*)d_in[5];
    const float* u2b = (const float*)d_in[6];
    const float* v11 = (const float*)d_in[7];
    const float* v12 = (const float*)d_in[8];
    const float* v21 = (const float*)d_in[9];
    const float* v22 = (const float*)d_in[10];
    const float* b1  = (const float*)d_in[11];
    const float* b2  = (const float*)d_in[12];
    float* out = (float*)d_out;

    u16* Y1   = (u16*)d_ws;                       // 8192*6656
    u16* Y2   = Y1 + (size_t)8192 * 6656;
    u16* xbf  = Y2 + (size_t)8192 * 6656;         // 8192*1024
    u16* u1bf = xbf + (size_t)8192 * 1024;        // 3072*1024
    u16* u2bf = u1bf + (size_t)3072 * 1024;
    u16* W1   = u2bf + (size_t)3072 * 1024;       // 512*6656
    u16* W2   = W1 + (size_t)512 * 6656;
    float* part = (float*)(W2 + (size_t)512 * 6656);

    const size_t base = (size_t)(W2 + (size_t)512 * 6656 - (u16*)d_ws) * 2;
    const size_t pbytes = (size_t)8192 * 1024 * 4;
    int nsplit = 1;
    if (ws_size >= base + 3 * pbytes) nsplit = 4;
    else if (ws_size >= base + pbytes) nsplit = 2;

    cvt_bf16<<<dim3(14336), 256, 0, stream>>>(x, u1w, u2w, xbf);
    prep_wcat<<<dim3(13312), 256, 0, stream>>>(v11, v12, v21, v22, b1, b2, W1, W2);

    gemm_bt<<<dim3(24, 64, 2), 256, 0, stream>>>(
        xbf, xbf, 1024, u1bf, u2bf, 1024, u1b, u2b, Y1, Y2, 6656, 3072, 1024);

    gating<<<dim3(8192), 256, 0, stream>>>(g1, g2, Y1, Y2);

    gemm2_split<<<dim3(4 * 64 * 2 * nsplit), 256, 0, stream>>>(
        Y1, Y2, W1, W2, out, part, nsplit);
    if (nsplit > 1)
        reduce_add<<<dim3(8192), 256, 0, stream>>>(
            (float4*)out, (const float4*)part, nsplit - 1);
}